// Round 2
// baseline (190.794 us; speedup 1.0000x reference)
//
#include <hip/hip_runtime.h>
#include <math.h>

// Problem constants
#define NRAYS        32768
#define MARCH_ITERS  64
#define EPS_         1e-4f
#define STEP_        ((1.0f + 1.0f/64.0f) / 64.0f)   // exact in fp32

typedef __attribute__((ext_vector_type(8)))  short    short8;   // 8 bf16
typedef __attribute__((ext_vector_type(4)))  float    float4v;  // C/D frag
typedef __attribute__((ext_vector_type(4)))  unsigned uint4v;

__device__ __forceinline__ short8 mk_frag(unsigned p0, unsigned p1,
                                          unsigned p2, unsigned p3) {
    uint4v v = {p0, p1, p2, p3};
    return __builtin_bit_cast(short8, v);
}

// One v_perm_b32: low16 = trunc-bf16(a), high16 = trunc-bf16(b).
__device__ __forceinline__ unsigned packbf(unsigned a, unsigned b) {
    return __builtin_amdgcn_perm(b, a, 0x07060302u);
}

// Exact 3-way truncation split: x == hi + mid + lo bit-exactly in fp32.
struct Split3 { unsigned h, m, l; };
__device__ __forceinline__ Split3 split3(float x) {
    unsigned xu = __float_as_uint(x);
    float xh = __uint_as_float(xu & 0xFFFF0000u);
    float r  = x - xh;                        // exact
    unsigned ru = __float_as_uint(r);
    float xm = __uint_as_float(ru & 0xFFFF0000u);
    float r2 = r - xm;                        // exact, fits bf16
    return { xu, ru, __float_as_uint(r2) };
}

// 2-way split: hi + residual (packbf of r truncates -> the mid limb).
struct Split2 { unsigned h, r; };
__device__ __forceinline__ Split2 split2(float x) {
    unsigned xu = __float_as_uint(x);
    float xh = __uint_as_float(xu & 0xFFFF0000u);
    float rr = x - xh;                        // exact residual
    return { xu, __float_as_uint(rr) };
}

// R16 (resubmit; R1 bench was an infra failure): LDS-pipe relief.
// R15 streamed BOTH W1 limb sets from LDS every iteration (march 24
// ds_read_b128/iter, tput 16/iter) -> ~100 us of per-CU LDS-pipe
// occupancy at 8 blocks/CU, which was the binding pipe (MfmaUtil 35%,
// VALUBusy 68%, HBM 0.1%, conflicts 0). Now A2h (the limb used TWICE
// per iter in both waves) lives in registers (+32 VGPR); only A2m
// (used once, march only) streams from LDS. In-loop LDS reads:
// march 24 -> 8, tput 16 -> 0. LDS is produced and consumed by wave0
// only, so the block barrier is gone. All arithmetic is bit-identical
// to R15 (same packbf of same W1 words, same MFMA accumulation order).
// 128-thread blocks: wave0 = march (serial), wave1 = tput (65 indep evals).
// MFMA layouts (R6-verified): A[row=lane&15][k=quad*8+j],
// B[k=quad*8+j][col=lane&15], C/D col=lane&15 row=quad*4+reg.
// L1 hidden assignment H(t,q,r)=32*(t>>1)+8q+4*(t&1)+r -> in-lane C1->B2.
// Precision: march L2 = 3 products (m,h)(h,m)(h,h); tput L2 = 2 products.
__global__ __launch_bounds__(128, 4) void sdf_w5_k(
    const float* __restrict__ rays,
    const float* __restrict__ W0,  const float* __restrict__ b0,
    const float* __restrict__ W1,  const float* __restrict__ b1,
    const float* __restrict__ W2,  const float* __restrict__ b2,
    const float* __restrict__ Wr0, const float* __restrict__ br0,
    const float* __restrict__ Wr1, const float* __restrict__ br1,
    float* __restrict__ out)
{
    __shared__ uint4v a2mLds[8 * 64];         // 8 KB: W1 mid-limb frags (wave0 only)

    const int lane = threadIdx.x & 63;
    const int kind = threadIdx.x >> 6;        // 0 = march, 1 = tput
    const int quad = lane >> 4;
    const int m    = lane & 15;
    const int rayBase = blockIdx.x * 16;

    // ---- per-lane ray (ray = rayBase + m, replicated over quads) ----
    const float* rp = rays + (rayBase + m) * 6;
    const float ox = rp[0], oy = rp[1], oz = rp[2];
    const float dx = rp[3], dy = rp[4], dz = rp[5];

    // ---- A1: exact W0^T/b0 limbs, uniform per-quad K-slots (R9-verified) ----
    short8 A1[4];
    {
        const float* wbase = (quad == 0) ? W0 : (quad == 1) ? (W0 + 64)
                           : (quad == 2) ? (W0 + 128) : b0;
        #pragma unroll
        for (int t = 0; t < 4; ++t) {
            int j = 32 * (t >> 1) + 8 * (m >> 2) + 4 * (t & 1) + (m & 3);
            Split3 s = split3(wbase[j]);
            unsigned hh = packbf(s.h, s.h);
            unsigned hm = packbf(s.h, s.m);
            unsigned ml = packbf(s.m, s.l);
            unsigned l0 = packbf(s.l, 0u);
            bool is3 = (quad == 3);
            A1[t] = mk_frag(is3 ? hm : hh, is3 ? l0 : hm, is3 ? 0u : ml, 0u);
        }
    }

    // ---- W1 limb staging: A2h -> registers (both waves); A2m -> LDS (wave0) ----
    short8 A2h[2][4];
    if (kind == 0) {
        // March wave: one pass over W1 builds both limbs (hi -> regs, mid -> LDS).
        #pragma unroll
        for (int h = 0; h < 2; ++h)
            #pragma unroll
            for (int t = 0; t < 4; ++t) {
                unsigned pm[4], ph[4];
                #pragma unroll
                for (int jp = 0; jp < 4; ++jp) {
                    int k0 = 32 * h + quad * 8 + 2 * jp;
                    int j2 = 16 * t + m;
                    Split2 a = split2(W1[k0 * 64 + j2]);
                    Split2 b = split2(W1[(k0 + 1) * 64 + j2]);
                    pm[jp] = packbf(a.r, b.r);   // trunc(residual) == mid limb
                    ph[jp] = packbf(a.h, b.h);   // trunc(full) == hi limb
                }
                a2mLds[(h * 4 + t) * 64 + lane] = (uint4v){pm[0], pm[1], pm[2], pm[3]};
                A2h[h][t] = mk_frag(ph[0], ph[1], ph[2], ph[3]);
            }
    } else {
        // Tput wave: hi limbs only, straight to registers. Zero LDS use.
        #pragma unroll
        for (int h = 0; h < 2; ++h)
            #pragma unroll
            for (int t = 0; t < 4; ++t) {
                unsigned ph[4];
                #pragma unroll
                for (int jp = 0; jp < 4; ++jp) {
                    int k0 = 32 * h + quad * 8 + 2 * jp;
                    int j2 = 16 * t + m;
                    ph[jp] = packbf(__float_as_uint(W1[k0 * 64 + j2]),
                                    __float_as_uint(W1[(k0 + 1) * 64 + j2]));
                }
                A2h[h][t] = mk_frag(ph[0], ph[1], ph[2], ph[3]);
            }
    }
    // No __syncthreads(): a2mLds is written and read by wave0 only
    // (same-wave LDS ordering is handled by lgkmcnt).

    // ---- b1 (C2 init) and W2 (L3), per-lane rows j2 = 16t+4q+r ----
    float4v b1v[4], w2v[4];
    #pragma unroll
    for (int t = 0; t < 4; ++t) {
        int base = 16 * t + 4 * quad;
        b1v[t] = (float4v){b1[base], b1[base + 1], b1[base + 2], b1[base + 3]};
        w2v[t] = (float4v){W2[base], W2[base + 1], W2[base + 2], W2[base + 3]};
    }
    const float b2s = b2[0];
    const float4v z4 = {0.f, 0.f, 0.f, 0.f};

    // ---- branchless exact B1 build (R9/R10-verified) ----
    auto buildB1 = [&](float px, float py, float pz) -> short8 {
        float c = (quad == 0) ? px : (quad == 1) ? py : pz;
        Split3 s = split3(c);
        unsigned d0 = packbf(s.h, s.m);
        unsigned d1 = packbf(s.l, s.h);
        unsigned d2 = packbf(s.m, s.h);
        if (quad == 3) { d0 = 0x3F803F80u; d1 = 0x00003F80u; d2 = 0u; }
        return mk_frag(d0, d1, d2, 0u);
    };

    // ---- shared front-end: pos -> exact L1 -> relu -> split2 pack ----
    auto front = [&](float px, float py, float pz, short8* BH, short8* BM) {
        short8 B1 = buildB1(px, py, pz);
        float4v C1[4];
        #pragma unroll
        for (int t = 0; t < 4; ++t)
            C1[t] = __builtin_amdgcn_mfma_f32_16x16x32_bf16(A1[t], B1, z4, 0, 0, 0);
        unsigned PH[4][2], PM[4][2];
        #pragma unroll
        for (int t = 0; t < 4; ++t) {
            float v0 = fmaxf(C1[t][0], 0.f), v1 = fmaxf(C1[t][1], 0.f);
            float v2 = fmaxf(C1[t][2], 0.f), v3 = fmaxf(C1[t][3], 0.f);
            unsigned u0 = __float_as_uint(v0), u1 = __float_as_uint(v1);
            unsigned u2 = __float_as_uint(v2), u3 = __float_as_uint(v3);
            PH[t][0] = packbf(u0, u1); PH[t][1] = packbf(u2, u3);
            float r0 = v0 - __uint_as_float(u0 & 0xFFFF0000u);
            float r1 = v1 - __uint_as_float(u1 & 0xFFFF0000u);
            float r2 = v2 - __uint_as_float(u2 & 0xFFFF0000u);
            float r3 = v3 - __uint_as_float(u3 & 0xFFFF0000u);
            PM[t][0] = packbf(__float_as_uint(r0), __float_as_uint(r1));
            PM[t][1] = packbf(__float_as_uint(r2), __float_as_uint(r3));
        }
        #pragma unroll
        for (int h = 0; h < 2; ++h) {
            BH[h] = mk_frag(PH[2 * h][0], PH[2 * h][1],
                            PH[2 * h + 1][0], PH[2 * h + 1][1]);
            BM[h] = mk_frag(PM[2 * h][0], PM[2 * h][1],
                            PM[2 * h + 1][0], PM[2 * h + 1][1]);
        }
    };

    // ---- L3: in-lane relu*W2, 2 cross-quad shuffles -> d at every lane ----
    auto l3 = [&](const float4v* C2) -> float {
        float q0 = 0.f, q1 = 0.f, q2 = 0.f, q3 = 0.f;
        #pragma unroll
        for (int t = 0; t < 4; ++t) {
            q0 = fmaf(fmaxf(C2[t][0], 0.f), w2v[t][0], q0);
            q1 = fmaf(fmaxf(C2[t][1], 0.f), w2v[t][1], q1);
            q2 = fmaf(fmaxf(C2[t][2], 0.f), w2v[t][2], q2);
            q3 = fmaf(fmaxf(C2[t][3], 0.f), w2v[t][3], q3);
        }
        float part = (q0 + q1) + (q2 + q3);
        part += __shfl_xor(part, 16, 64);
        part += __shfl_xor(part, 32, 64);
        return b2s + part;
    };

    auto ldsA2m = [&](int h, int t) -> short8 {
        return __builtin_bit_cast(short8, a2mLds[(h * 4 + t) * 64 + lane]);
    };

    if (kind == 0) {
        // =================== MARCH wave: 64 sequential evals ===============
        bool  hit = false;
        float cd  = 0.f;
        #pragma unroll 1
        for (int it = 0; it < MARCH_ITERS; ++it) {
            if (__all(hit)) break;
            short8 BH[2], BM[2];
            front(fmaf(dx, cd, ox), fmaf(dy, cd, oy), fmaf(dz, cd, oz), BH, BM);
            // L2: 3 products, small first: (m,h)(h,m)(h,h); 24 MFMAs.
            // A2m streams from LDS (8 reads/iter); A2h comes from registers.
            float4v C2[4];
            #pragma unroll
            for (int t = 0; t < 4; ++t) C2[t] = b1v[t];
            #pragma unroll
            for (int h = 0; h < 2; ++h)
                #pragma unroll
                for (int t = 0; t < 4; ++t)
                    C2[t] = __builtin_amdgcn_mfma_f32_16x16x32_bf16(
                        ldsA2m(h, t), BH[h], C2[t], 0, 0, 0);
            #pragma unroll
            for (int h = 0; h < 2; ++h)
                #pragma unroll
                for (int t = 0; t < 4; ++t)
                    C2[t] = __builtin_amdgcn_mfma_f32_16x16x32_bf16(
                        A2h[h][t], BM[h], C2[t], 0, 0, 0);
            #pragma unroll
            for (int h = 0; h < 2; ++h)
                #pragma unroll
                for (int t = 0; t < 4; ++t)
                    C2[t] = __builtin_amdgcn_mfma_f32_16x16x32_bf16(
                        A2h[h][t], BH[h], C2[t], 0, 0, 0);
            float dm = l3(C2);
            bool c = (dm < EPS_) && (cd >= 0.f) && (cd <= 1.f);
            hit = hit || c;
            if (!hit) cd += dm;
        }

        // ---- reflection net: quad q handles hidden j in [16q, 16q+16) ----
        const float px = fmaf(dx, cd, ox), py = fmaf(dy, cd, oy), pz = fmaf(dz, cd, oz);
        float r0 = 0.f, r1 = 0.f, r2 = 0.f;
        #pragma unroll 4
        for (int jj = 0; jj < 16; ++jj) {
            int j = quad * 16 + jj;
            float a = fmaf(px, Wr0[j],
                      fmaf(py, Wr0[64 + j],
                      fmaf(pz, Wr0[128 + j],
                      fmaf(dx, Wr0[192 + j],
                      fmaf(dy, Wr0[256 + j],
                      fmaf(dz, Wr0[320 + j], br0[j]))))));
            a = fmaxf(a, 0.f);
            r0 = fmaf(a, Wr1[j * 3 + 0], r0);
            r1 = fmaf(a, Wr1[j * 3 + 1], r1);
            r2 = fmaf(a, Wr1[j * 3 + 2], r2);
        }
        r0 += __shfl_xor(r0, 16, 64); r0 += __shfl_xor(r0, 32, 64);
        r1 += __shfl_xor(r1, 16, 64); r1 += __shfl_xor(r1, 32, 64);
        r2 += __shfl_xor(r2, 16, 64); r2 += __shfl_xor(r2, 32, 64);
        r0 = 1.f / (1.f + expf(-(r0 + br1[0])));
        r1 = 1.f / (1.f + expf(-(r1 + br1[1])));
        r2 = 1.f / (1.f + expf(-(r2 + br1[2])));
        if (!hit) { r0 = 0.f; r1 = 0.f; r2 = 0.f; }
        if (lane < 16) {
            float* op = out + (rayBase + lane) * 4;
            op[0] = r0; op[1] = r1; op[2] = r2;
        }
    } else {
        // =================== TPUT wave: 65 independent evals ===============
        // i=0 at origin (== reference curr_min0), then t = STEP*i. unroll-1.
        // Zero LDS traffic: both L2 products use register-resident A2h.
        float cm = 3.4e38f;
        #pragma unroll 1
        for (int i = 0; i <= 64; ++i) {
            float ti = STEP_ * (float)i;
            short8 BH[2], BM[2];
            front(fmaf(dx, ti, ox), fmaf(dy, ti, oy), fmaf(dz, ti, oz), BH, BM);
            // L2: 2 products (h,m)(h,h); 16 MFMAs.
            float4v C2[4];
            #pragma unroll
            for (int t = 0; t < 4; ++t) C2[t] = b1v[t];
            #pragma unroll
            for (int h = 0; h < 2; ++h)
                #pragma unroll
                for (int t = 0; t < 4; ++t)
                    C2[t] = __builtin_amdgcn_mfma_f32_16x16x32_bf16(
                        A2h[h][t], BM[h], C2[t], 0, 0, 0);
            #pragma unroll
            for (int h = 0; h < 2; ++h)
                #pragma unroll
                for (int t = 0; t < 4; ++t)
                    C2[t] = __builtin_amdgcn_mfma_f32_16x16x32_bf16(
                        A2h[h][t], BH[h], C2[t], 0, 0, 0);
            float dt = l3(C2);
            cm = fminf(cm, dt);
        }
        if (lane < 16)
            out[(rayBase + lane) * 4 + 3] = cm;
    }
}

extern "C" void kernel_launch(void* const* d_in, const int* in_sizes, int n_in,
                              void* d_out, int out_size, void* d_ws, size_t ws_size,
                              hipStream_t stream) {
    const float* rays = (const float*)d_in[0];
    const float* W0   = (const float*)d_in[1];
    const float* b0   = (const float*)d_in[2];
    const float* W1   = (const float*)d_in[3];
    const float* b1   = (const float*)d_in[4];
    const float* W2   = (const float*)d_in[5];
    const float* b2   = (const float*)d_in[6];
    const float* Wr0  = (const float*)d_in[7];
    const float* br0  = (const float*)d_in[8];
    const float* Wr1  = (const float*)d_in[9];
    const float* br1  = (const float*)d_in[10];
    float* out = (float*)d_out;

    // 2048 blocks x 128 threads: wave0 = march, wave1 = tput per 16 rays.
    // A2h in registers (both waves); A2m in LDS (8 KB/block, wave0 only).
    // __launch_bounds__(128,4) -> 4 waves/SIMD; grid fully co-resident.
    hipLaunchKernelGGL(sdf_w5_k, dim3(NRAYS / 16), dim3(128), 0, stream,
                       rays, W0, b0, W1, b1, W2, b2, Wr0, br0, Wr1, br1, out);
}

// Round 3
// 188.753 us; speedup vs baseline: 1.0108x; 1.0108x over previous
//
#include <hip/hip_runtime.h>
#include <math.h>

// Problem constants
#define NRAYS        32768
#define MARCH_ITERS  64
#define EPS_         1e-4f
#define STEP_        ((1.0f + 1.0f/64.0f) / 64.0f)   // exact in fp32

typedef __attribute__((ext_vector_type(8)))  short    short8;   // 8 bf16
typedef __attribute__((ext_vector_type(4)))  float    float4v;  // C/D frag
typedef __attribute__((ext_vector_type(4)))  unsigned uint4v;

__device__ __forceinline__ short8 mk_frag(unsigned p0, unsigned p1,
                                          unsigned p2, unsigned p3) {
    uint4v v = {p0, p1, p2, p3};
    return __builtin_bit_cast(short8, v);
}

// One v_perm_b32: low16 = trunc-bf16(a), high16 = trunc-bf16(b).
__device__ __forceinline__ unsigned packbf(unsigned a, unsigned b) {
    return __builtin_amdgcn_perm(b, a, 0x07060302u);
}

// Exact 3-way truncation split: x == hi + mid + lo bit-exactly in fp32.
struct Split3 { unsigned h, m, l; };
__device__ __forceinline__ Split3 split3(float x) {
    unsigned xu = __float_as_uint(x);
    float xh = __uint_as_float(xu & 0xFFFF0000u);
    float r  = x - xh;                        // exact
    unsigned ru = __float_as_uint(r);
    float xm = __uint_as_float(ru & 0xFFFF0000u);
    float r2 = r - xm;                        // exact, fits bf16
    return { xu, ru, __float_as_uint(r2) };
}

// 2-way split: hi + residual (packbf of r truncates -> the mid limb).
struct Split2 { unsigned h, r; };
__device__ __forceinline__ Split2 split2(float x) {
    unsigned xu = __float_as_uint(x);
    float xh = __uint_as_float(xu & 0xFFFF0000u);
    float rr = x - xh;                        // exact residual
    return { xu, __float_as_uint(rr) };
}

// R17: R16 post-mortem showed the A2h->register move never happened:
// VGPR_Count stayed 64 (the 8-waves/EU allocation) and WRITE_SIZE blew up
// 512KB -> 9216KB = A2h spilled to scratch (launch_bounds' 2nd arg is only
// a MINIMUM waves/EU; the backend still targeted 8/EU and spilled rather
// than allocate 96+). Fix: amdgpu_waves_per_eu(4,4) pins the occupancy
// target to exactly 4 waves/EU -> 128-VGPR budget, no spill incentive.
// Observed avg occupancy was ~2.4 waves/SIMD, below the 4 cap, so pinning
// costs nothing. Structure unchanged from R16:
//   A2h (W1 hi limbs, used 2x/iter in BOTH waves) -> 32 loop-carried VGPRs;
//   A2m (mid limbs, 1x/iter, march only)          -> 8 KB LDS;
//   in-loop ds_read_b128: march 24 -> 8, tput 16 -> 0; no __syncthreads().
// All arithmetic bit-identical to R15/R16 (same packbf of same W1 words,
// same MFMA accumulation order) -> absmax must stay 0.00390625.
// 128-thread blocks: wave0 = march (serial), wave1 = tput (65 indep evals).
// MFMA layouts (R6-verified): A[row=lane&15][k=quad*8+j],
// B[k=quad*8+j][col=lane&15], C/D col=lane&15 row=quad*4+reg.
// L1 hidden assignment H(t,q,r)=32*(t>>1)+8q+4*(t&1)+r -> in-lane C1->B2.
// Precision: march L2 = 3 products (m,h)(h,m)(h,h); tput L2 = 2 products.
__global__ __launch_bounds__(128)
__attribute__((amdgpu_waves_per_eu(4, 4)))
void sdf_w6_k(
    const float* __restrict__ rays,
    const float* __restrict__ W0,  const float* __restrict__ b0,
    const float* __restrict__ W1,  const float* __restrict__ b1,
    const float* __restrict__ W2,  const float* __restrict__ b2,
    const float* __restrict__ Wr0, const float* __restrict__ br0,
    const float* __restrict__ Wr1, const float* __restrict__ br1,
    float* __restrict__ out)
{
    __shared__ uint4v a2mLds[8 * 64];         // 8 KB: W1 mid-limb frags (wave0 only)

    const int lane = threadIdx.x & 63;
    const int kind = threadIdx.x >> 6;        // 0 = march, 1 = tput
    const int quad = lane >> 4;
    const int m    = lane & 15;
    const int rayBase = blockIdx.x * 16;

    // ---- per-lane ray (ray = rayBase + m, replicated over quads) ----
    const float* rp = rays + (rayBase + m) * 6;
    const float ox = rp[0], oy = rp[1], oz = rp[2];
    const float dx = rp[3], dy = rp[4], dz = rp[5];

    // ---- A1: exact W0^T/b0 limbs, uniform per-quad K-slots (R9-verified) ----
    short8 A1[4];
    {
        const float* wbase = (quad == 0) ? W0 : (quad == 1) ? (W0 + 64)
                           : (quad == 2) ? (W0 + 128) : b0;
        #pragma unroll
        for (int t = 0; t < 4; ++t) {
            int j = 32 * (t >> 1) + 8 * (m >> 2) + 4 * (t & 1) + (m & 3);
            Split3 s = split3(wbase[j]);
            unsigned hh = packbf(s.h, s.h);
            unsigned hm = packbf(s.h, s.m);
            unsigned ml = packbf(s.m, s.l);
            unsigned l0 = packbf(s.l, 0u);
            bool is3 = (quad == 3);
            A1[t] = mk_frag(is3 ? hm : hh, is3 ? l0 : hm, is3 ? 0u : ml, 0u);
        }
    }

    // ---- W1 limb staging: A2h -> registers (both waves); A2m -> LDS (wave0) ----
    short8 A2h[2][4];
    if (kind == 0) {
        // March wave: one pass over W1 builds both limbs (hi -> regs, mid -> LDS).
        #pragma unroll
        for (int h = 0; h < 2; ++h)
            #pragma unroll
            for (int t = 0; t < 4; ++t) {
                unsigned pm[4], ph[4];
                #pragma unroll
                for (int jp = 0; jp < 4; ++jp) {
                    int k0 = 32 * h + quad * 8 + 2 * jp;
                    int j2 = 16 * t + m;
                    Split2 a = split2(W1[k0 * 64 + j2]);
                    Split2 b = split2(W1[(k0 + 1) * 64 + j2]);
                    pm[jp] = packbf(a.r, b.r);   // trunc(residual) == mid limb
                    ph[jp] = packbf(a.h, b.h);   // trunc(full) == hi limb
                }
                a2mLds[(h * 4 + t) * 64 + lane] = (uint4v){pm[0], pm[1], pm[2], pm[3]};
                A2h[h][t] = mk_frag(ph[0], ph[1], ph[2], ph[3]);
            }
    } else {
        // Tput wave: hi limbs only, straight to registers. Zero LDS use.
        #pragma unroll
        for (int h = 0; h < 2; ++h)
            #pragma unroll
            for (int t = 0; t < 4; ++t) {
                unsigned ph[4];
                #pragma unroll
                for (int jp = 0; jp < 4; ++jp) {
                    int k0 = 32 * h + quad * 8 + 2 * jp;
                    int j2 = 16 * t + m;
                    ph[jp] = packbf(__float_as_uint(W1[k0 * 64 + j2]),
                                    __float_as_uint(W1[(k0 + 1) * 64 + j2]));
                }
                A2h[h][t] = mk_frag(ph[0], ph[1], ph[2], ph[3]);
            }
    }
    // No __syncthreads(): a2mLds is written and read by wave0 only
    // (same-wave LDS ordering is handled by lgkmcnt).

    // ---- b1 (C2 init) and W2 (L3), per-lane rows j2 = 16t+4q+r ----
    float4v b1v[4], w2v[4];
    #pragma unroll
    for (int t = 0; t < 4; ++t) {
        int base = 16 * t + 4 * quad;
        b1v[t] = (float4v){b1[base], b1[base + 1], b1[base + 2], b1[base + 3]};
        w2v[t] = (float4v){W2[base], W2[base + 1], W2[base + 2], W2[base + 3]};
    }
    const float b2s = b2[0];
    const float4v z4 = {0.f, 0.f, 0.f, 0.f};

    // ---- branchless exact B1 build (R9/R10-verified) ----
    auto buildB1 = [&](float px, float py, float pz) -> short8 {
        float c = (quad == 0) ? px : (quad == 1) ? py : pz;
        Split3 s = split3(c);
        unsigned d0 = packbf(s.h, s.m);
        unsigned d1 = packbf(s.l, s.h);
        unsigned d2 = packbf(s.m, s.h);
        if (quad == 3) { d0 = 0x3F803F80u; d1 = 0x00003F80u; d2 = 0u; }
        return mk_frag(d0, d1, d2, 0u);
    };

    // ---- shared front-end: pos -> exact L1 -> relu -> split2 pack ----
    auto front = [&](float px, float py, float pz, short8* BH, short8* BM) {
        short8 B1 = buildB1(px, py, pz);
        float4v C1[4];
        #pragma unroll
        for (int t = 0; t < 4; ++t)
            C1[t] = __builtin_amdgcn_mfma_f32_16x16x32_bf16(A1[t], B1, z4, 0, 0, 0);
        unsigned PH[4][2], PM[4][2];
        #pragma unroll
        for (int t = 0; t < 4; ++t) {
            float v0 = fmaxf(C1[t][0], 0.f), v1 = fmaxf(C1[t][1], 0.f);
            float v2 = fmaxf(C1[t][2], 0.f), v3 = fmaxf(C1[t][3], 0.f);
            unsigned u0 = __float_as_uint(v0), u1 = __float_as_uint(v1);
            unsigned u2 = __float_as_uint(v2), u3 = __float_as_uint(v3);
            PH[t][0] = packbf(u0, u1); PH[t][1] = packbf(u2, u3);
            float r0 = v0 - __uint_as_float(u0 & 0xFFFF0000u);
            float r1 = v1 - __uint_as_float(u1 & 0xFFFF0000u);
            float r2 = v2 - __uint_as_float(u2 & 0xFFFF0000u);
            float r3 = v3 - __uint_as_float(u3 & 0xFFFF0000u);
            PM[t][0] = packbf(__float_as_uint(r0), __float_as_uint(r1));
            PM[t][1] = packbf(__float_as_uint(r2), __float_as_uint(r3));
        }
        #pragma unroll
        for (int h = 0; h < 2; ++h) {
            BH[h] = mk_frag(PH[2 * h][0], PH[2 * h][1],
                            PH[2 * h + 1][0], PH[2 * h + 1][1]);
            BM[h] = mk_frag(PM[2 * h][0], PM[2 * h][1],
                            PM[2 * h + 1][0], PM[2 * h + 1][1]);
        }
    };

    // ---- L3: in-lane relu*W2, 2 cross-quad shuffles -> d at every lane ----
    auto l3 = [&](const float4v* C2) -> float {
        float q0 = 0.f, q1 = 0.f, q2 = 0.f, q3 = 0.f;
        #pragma unroll
        for (int t = 0; t < 4; ++t) {
            q0 = fmaf(fmaxf(C2[t][0], 0.f), w2v[t][0], q0);
            q1 = fmaf(fmaxf(C2[t][1], 0.f), w2v[t][1], q1);
            q2 = fmaf(fmaxf(C2[t][2], 0.f), w2v[t][2], q2);
            q3 = fmaf(fmaxf(C2[t][3], 0.f), w2v[t][3], q3);
        }
        float part = (q0 + q1) + (q2 + q3);
        part += __shfl_xor(part, 16, 64);
        part += __shfl_xor(part, 32, 64);
        return b2s + part;
    };

    auto ldsA2m = [&](int h, int t) -> short8 {
        return __builtin_bit_cast(short8, a2mLds[(h * 4 + t) * 64 + lane]);
    };

    if (kind == 0) {
        // =================== MARCH wave: 64 sequential evals ===============
        bool  hit = false;
        float cd  = 0.f;
        #pragma unroll 1
        for (int it = 0; it < MARCH_ITERS; ++it) {
            if (__all(hit)) break;
            short8 BH[2], BM[2];
            front(fmaf(dx, cd, ox), fmaf(dy, cd, oy), fmaf(dz, cd, oz), BH, BM);
            // L2: 3 products, small first: (m,h)(h,m)(h,h); 24 MFMAs.
            // A2m streams from LDS (8 reads/iter); A2h comes from registers.
            float4v C2[4];
            #pragma unroll
            for (int t = 0; t < 4; ++t) C2[t] = b1v[t];
            #pragma unroll
            for (int h = 0; h < 2; ++h)
                #pragma unroll
                for (int t = 0; t < 4; ++t)
                    C2[t] = __builtin_amdgcn_mfma_f32_16x16x32_bf16(
                        ldsA2m(h, t), BH[h], C2[t], 0, 0, 0);
            #pragma unroll
            for (int h = 0; h < 2; ++h)
                #pragma unroll
                for (int t = 0; t < 4; ++t)
                    C2[t] = __builtin_amdgcn_mfma_f32_16x16x32_bf16(
                        A2h[h][t], BM[h], C2[t], 0, 0, 0);
            #pragma unroll
            for (int h = 0; h < 2; ++h)
                #pragma unroll
                for (int t = 0; t < 4; ++t)
                    C2[t] = __builtin_amdgcn_mfma_f32_16x16x32_bf16(
                        A2h[h][t], BH[h], C2[t], 0, 0, 0);
            float dm = l3(C2);
            bool c = (dm < EPS_) && (cd >= 0.f) && (cd <= 1.f);
            hit = hit || c;
            if (!hit) cd += dm;
        }

        // ---- reflection net: quad q handles hidden j in [16q, 16q+16) ----
        const float px = fmaf(dx, cd, ox), py = fmaf(dy, cd, oy), pz = fmaf(dz, cd, oz);
        float r0 = 0.f, r1 = 0.f, r2 = 0.f;
        #pragma unroll 4
        for (int jj = 0; jj < 16; ++jj) {
            int j = quad * 16 + jj;
            float a = fmaf(px, Wr0[j],
                      fmaf(py, Wr0[64 + j],
                      fmaf(pz, Wr0[128 + j],
                      fmaf(dx, Wr0[192 + j],
                      fmaf(dy, Wr0[256 + j],
                      fmaf(dz, Wr0[320 + j], br0[j]))))));
            a = fmaxf(a, 0.f);
            r0 = fmaf(a, Wr1[j * 3 + 0], r0);
            r1 = fmaf(a, Wr1[j * 3 + 1], r1);
            r2 = fmaf(a, Wr1[j * 3 + 2], r2);
        }
        r0 += __shfl_xor(r0, 16, 64); r0 += __shfl_xor(r0, 32, 64);
        r1 += __shfl_xor(r1, 16, 64); r1 += __shfl_xor(r1, 32, 64);
        r2 += __shfl_xor(r2, 16, 64); r2 += __shfl_xor(r2, 32, 64);
        r0 = 1.f / (1.f + expf(-(r0 + br1[0])));
        r1 = 1.f / (1.f + expf(-(r1 + br1[1])));
        r2 = 1.f / (1.f + expf(-(r2 + br1[2])));
        if (!hit) { r0 = 0.f; r1 = 0.f; r2 = 0.f; }
        if (lane < 16) {
            float* op = out + (rayBase + lane) * 4;
            op[0] = r0; op[1] = r1; op[2] = r2;
        }
    } else {
        // =================== TPUT wave: 65 independent evals ===============
        // i=0 at origin (== reference curr_min0), then t = STEP*i. unroll-1.
        // Zero LDS traffic: both L2 products use register-resident A2h.
        float cm = 3.4e38f;
        #pragma unroll 1
        for (int i = 0; i <= 64; ++i) {
            float ti = STEP_ * (float)i;
            short8 BH[2], BM[2];
            front(fmaf(dx, ti, ox), fmaf(dy, ti, oy), fmaf(dz, ti, oz), BH, BM);
            // L2: 2 products (h,m)(h,h); 16 MFMAs.
            float4v C2[4];
            #pragma unroll
            for (int t = 0; t < 4; ++t) C2[t] = b1v[t];
            #pragma unroll
            for (int h = 0; h < 2; ++h)
                #pragma unroll
                for (int t = 0; t < 4; ++t)
                    C2[t] = __builtin_amdgcn_mfma_f32_16x16x32_bf16(
                        A2h[h][t], BM[h], C2[t], 0, 0, 0);
            #pragma unroll
            for (int h = 0; h < 2; ++h)
                #pragma unroll
                for (int t = 0; t < 4; ++t)
                    C2[t] = __builtin_amdgcn_mfma_f32_16x16x32_bf16(
                        A2h[h][t], BH[h], C2[t], 0, 0, 0);
            float dt = l3(C2);
            cm = fminf(cm, dt);
        }
        if (lane < 16)
            out[(rayBase + lane) * 4 + 3] = cm;
    }
}

extern "C" void kernel_launch(void* const* d_in, const int* in_sizes, int n_in,
                              void* d_out, int out_size, void* d_ws, size_t ws_size,
                              hipStream_t stream) {
    const float* rays = (const float*)d_in[0];
    const float* W0   = (const float*)d_in[1];
    const float* b0   = (const float*)d_in[2];
    const float* W1   = (const float*)d_in[3];
    const float* b1   = (const float*)d_in[4];
    const float* W2   = (const float*)d_in[5];
    const float* b2   = (const float*)d_in[6];
    const float* Wr0  = (const float*)d_in[7];
    const float* br0  = (const float*)d_in[8];
    const float* Wr1  = (const float*)d_in[9];
    const float* br1  = (const float*)d_in[10];
    float* out = (float*)d_out;

    // 2048 blocks x 128 threads: wave0 = march, wave1 = tput per 16 rays.
    // A2h in registers (both waves); A2m in LDS (8 KB/block, wave0 only).
    // amdgpu_waves_per_eu(4,4): pin allocator to the 128-VGPR budget so
    // A2h actually lands in VGPRs (R16 spilled at a 64-VGPR target).
    hipLaunchKernelGGL(sdf_w6_k, dim3(NRAYS / 16), dim3(128), 0, stream,
                       rays, W0, b0, W1, b1, W2, b2, Wr0, br0, Wr1, br1, out);
}

// Round 4
// 188.175 us; speedup vs baseline: 1.0139x; 1.0031x over previous
//
#include <hip/hip_runtime.h>
#include <math.h>

// Problem constants
#define NRAYS        32768
#define MARCH_ITERS  64
#define EPS_         1e-4f
#define STEP_        ((1.0f + 1.0f/64.0f) / 64.0f)   // exact in fp32

typedef __attribute__((ext_vector_type(8)))  short    short8;   // 8 bf16
typedef __attribute__((ext_vector_type(4)))  float    float4v;  // C/D frag
typedef __attribute__((ext_vector_type(4)))  unsigned uint4v;

__device__ __forceinline__ short8 mk_frag(unsigned p0, unsigned p1,
                                          unsigned p2, unsigned p3) {
    uint4v v = {p0, p1, p2, p3};
    return __builtin_bit_cast(short8, v);
}

// One v_perm_b32: low16 = trunc-bf16(a), high16 = trunc-bf16(b).
__device__ __forceinline__ unsigned packbf(unsigned a, unsigned b) {
    return __builtin_amdgcn_perm(b, a, 0x07060302u);
}

// Exact 3-way truncation split: x == hi + mid + lo bit-exactly in fp32.
struct Split3 { unsigned h, m, l; };
__device__ __forceinline__ Split3 split3(float x) {
    unsigned xu = __float_as_uint(x);
    float xh = __uint_as_float(xu & 0xFFFF0000u);
    float r  = x - xh;                        // exact
    unsigned ru = __float_as_uint(r);
    float xm = __uint_as_float(ru & 0xFFFF0000u);
    float r2 = r - xm;                        // exact, fits bf16
    return { xu, ru, __float_as_uint(r2) };
}

// 2-way split: hi + residual (packbf of r truncates -> the mid limb).
struct Split2 { unsigned h, r; };
__device__ __forceinline__ Split2 split2(float x) {
    unsigned xu = __float_as_uint(x);
    float xh = __uint_as_float(xu & 0xFFFF0000u);
    float rr = x - xh;                        // exact residual
    return { xu, __float_as_uint(rr) };
}

// R18: structural split. R16/R17 post-mortems: total loop-live demand is
// ~175 VGPRs (A1 16 + A2h 32 + A2m 32 + b1v 16 + w2v 16 + C2 16 + BH/BM 16
// + ray/temps ~30) -- over the 128 budget of waves_per_eu(4,4), so the
// allocator spilled (WRITE_SIZE 9.2 MB) no matter what. And R15's real
// bottleneck is exposed per-iter latency: 127us/64 iters = 4.8k cyc/eval
// vs ~400 cyc of true chain -- register starvation serialized dozens of
// ~120-cyc LDS round-trips per iteration with only ~2.4 waves/SIMD to
// hide them (the 35/68 MfmaUtil/VALUBusy readings are any-of-4-SIMDs
// semantics; per-SIMD pipes were ~10%/18% -- nothing was saturated).
// Fix: march and tput waves share nothing but read-only weights, so give
// each its OWN single-wave block: 4096 blocks x 64 threads, even = march,
// odd = tput. Zero LDS, zero barriers, zero in-loop memory traffic;
// amdgpu_waves_per_eu(2,2) -> 256-VGPR budget fits the ~175-reg demand
// (2 waves/SIMD is also the occupancy sweet spot: 2 x ~220 VALU-cyc/iter
// saturates the VALU pipe). Per-eval MFMA accumulation order is EXACTLY
// R15's -> absmax must stay 0.00390625.
// MFMA layouts (R6-verified): A[row=lane&15][k=quad*8+j],
// B[k=quad*8+j][col=lane&15], C/D col=lane&15 row=quad*4+reg.
// L1 hidden assignment H(t,q,r)=32*(t>>1)+8q+4*(t&1)+r -> in-lane C1->B2.
// Precision: march L2 = 3 products (m,h)(h,m)(h,h); tput L2 = 2 products.
__global__ __launch_bounds__(64)
__attribute__((amdgpu_waves_per_eu(2, 2)))
void sdf_w7_k(
    const float* __restrict__ rays,
    const float* __restrict__ W0,  const float* __restrict__ b0,
    const float* __restrict__ W1,  const float* __restrict__ b1,
    const float* __restrict__ W2,  const float* __restrict__ b2,
    const float* __restrict__ Wr0, const float* __restrict__ br0,
    const float* __restrict__ Wr1, const float* __restrict__ br1,
    float* __restrict__ out)
{
    const int lane = threadIdx.x;             // 0..63, one wave per block
    const int kind = blockIdx.x & 1;          // 0 = march, 1 = tput
    const int quad = lane >> 4;
    const int m    = lane & 15;
    const int rayBase = (blockIdx.x >> 1) * 16;

    // ---- per-lane ray (ray = rayBase + m, replicated over quads) ----
    const float* rp = rays + (rayBase + m) * 6;
    const float ox = rp[0], oy = rp[1], oz = rp[2];
    const float dx = rp[3], dy = rp[4], dz = rp[5];

    // ---- A1: exact W0^T/b0 limbs, uniform per-quad K-slots (R9-verified) ----
    short8 A1[4];
    {
        const float* wbase = (quad == 0) ? W0 : (quad == 1) ? (W0 + 64)
                           : (quad == 2) ? (W0 + 128) : b0;
        #pragma unroll
        for (int t = 0; t < 4; ++t) {
            int j = 32 * (t >> 1) + 8 * (m >> 2) + 4 * (t & 1) + (m & 3);
            Split3 s = split3(wbase[j]);
            unsigned hh = packbf(s.h, s.h);
            unsigned hm = packbf(s.h, s.m);
            unsigned ml = packbf(s.m, s.l);
            unsigned l0 = packbf(s.l, 0u);
            bool is3 = (quad == 3);
            A1[t] = mk_frag(is3 ? hm : hh, is3 ? l0 : hm, is3 ? 0u : ml, 0u);
        }
    }

    // ---- b1 (C2 init) and W2 (L3), per-lane rows j2 = 16t+4q+r ----
    float4v b1v[4], w2v[4];
    #pragma unroll
    for (int t = 0; t < 4; ++t) {
        int base = 16 * t + 4 * quad;
        b1v[t] = (float4v){b1[base], b1[base + 1], b1[base + 2], b1[base + 3]};
        w2v[t] = (float4v){W2[base], W2[base + 1], W2[base + 2], W2[base + 3]};
    }
    const float b2s = b2[0];
    const float4v z4 = {0.f, 0.f, 0.f, 0.f};

    // ---- branchless exact B1 build (R9/R10-verified) ----
    auto buildB1 = [&](float px, float py, float pz) -> short8 {
        float c = (quad == 0) ? px : (quad == 1) ? py : pz;
        Split3 s = split3(c);
        unsigned d0 = packbf(s.h, s.m);
        unsigned d1 = packbf(s.l, s.h);
        unsigned d2 = packbf(s.m, s.h);
        if (quad == 3) { d0 = 0x3F803F80u; d1 = 0x00003F80u; d2 = 0u; }
        return mk_frag(d0, d1, d2, 0u);
    };

    // ---- shared front-end: pos -> exact L1 -> relu -> split2 pack ----
    auto front = [&](float px, float py, float pz, short8* BH, short8* BM) {
        short8 B1 = buildB1(px, py, pz);
        float4v C1[4];
        #pragma unroll
        for (int t = 0; t < 4; ++t)
            C1[t] = __builtin_amdgcn_mfma_f32_16x16x32_bf16(A1[t], B1, z4, 0, 0, 0);
        unsigned PH[4][2], PM[4][2];
        #pragma unroll
        for (int t = 0; t < 4; ++t) {
            float v0 = fmaxf(C1[t][0], 0.f), v1 = fmaxf(C1[t][1], 0.f);
            float v2 = fmaxf(C1[t][2], 0.f), v3 = fmaxf(C1[t][3], 0.f);
            unsigned u0 = __float_as_uint(v0), u1 = __float_as_uint(v1);
            unsigned u2 = __float_as_uint(v2), u3 = __float_as_uint(v3);
            PH[t][0] = packbf(u0, u1); PH[t][1] = packbf(u2, u3);
            float r0 = v0 - __uint_as_float(u0 & 0xFFFF0000u);
            float r1 = v1 - __uint_as_float(u1 & 0xFFFF0000u);
            float r2 = v2 - __uint_as_float(u2 & 0xFFFF0000u);
            float r3 = v3 - __uint_as_float(u3 & 0xFFFF0000u);
            PM[t][0] = packbf(__float_as_uint(r0), __float_as_uint(r1));
            PM[t][1] = packbf(__float_as_uint(r2), __float_as_uint(r3));
        }
        #pragma unroll
        for (int h = 0; h < 2; ++h) {
            BH[h] = mk_frag(PH[2 * h][0], PH[2 * h][1],
                            PH[2 * h + 1][0], PH[2 * h + 1][1]);
            BM[h] = mk_frag(PM[2 * h][0], PM[2 * h][1],
                            PM[2 * h + 1][0], PM[2 * h + 1][1]);
        }
    };

    // ---- L3: in-lane relu*W2, 2 cross-quad shuffles -> d at every lane ----
    auto l3 = [&](const float4v* C2) -> float {
        float q0 = 0.f, q1 = 0.f, q2 = 0.f, q3 = 0.f;
        #pragma unroll
        for (int t = 0; t < 4; ++t) {
            q0 = fmaf(fmaxf(C2[t][0], 0.f), w2v[t][0], q0);
            q1 = fmaf(fmaxf(C2[t][1], 0.f), w2v[t][1], q1);
            q2 = fmaf(fmaxf(C2[t][2], 0.f), w2v[t][2], q2);
            q3 = fmaf(fmaxf(C2[t][3], 0.f), w2v[t][3], q3);
        }
        float part = (q0 + q1) + (q2 + q3);
        part += __shfl_xor(part, 16, 64);
        part += __shfl_xor(part, 32, 64);
        return b2s + part;
    };

    if (kind == 0) {
        // =================== MARCH block: 64 sequential evals ==============
        // Both W1 limb sets live in registers: A2h (hi) + A2m (mid), 64 regs.
        short8 A2h[2][4], A2m[2][4];
        #pragma unroll
        for (int h = 0; h < 2; ++h)
            #pragma unroll
            for (int t = 0; t < 4; ++t) {
                unsigned pm[4], ph[4];
                #pragma unroll
                for (int jp = 0; jp < 4; ++jp) {
                    int k0 = 32 * h + quad * 8 + 2 * jp;
                    int j2 = 16 * t + m;
                    Split2 a = split2(W1[k0 * 64 + j2]);
                    Split2 b = split2(W1[(k0 + 1) * 64 + j2]);
                    pm[jp] = packbf(a.r, b.r);   // trunc(residual) == mid limb
                    ph[jp] = packbf(a.h, b.h);   // trunc(full) == hi limb
                }
                A2m[h][t] = mk_frag(pm[0], pm[1], pm[2], pm[3]);
                A2h[h][t] = mk_frag(ph[0], ph[1], ph[2], ph[3]);
            }

        bool  hit = false;
        float cd  = 0.f;
        #pragma unroll 1
        for (int it = 0; it < MARCH_ITERS; ++it) {
            if (__all(hit)) break;
            short8 BH[2], BM[2];
            front(fmaf(dx, cd, ox), fmaf(dy, cd, oy), fmaf(dz, cd, oz), BH, BM);
            // L2: 3 products, small first: (m,h)(h,m)(h,h); 24 MFMAs.
            // Same accumulation order as R15 -> bit-identical.
            float4v C2[4];
            #pragma unroll
            for (int t = 0; t < 4; ++t) C2[t] = b1v[t];
            #pragma unroll
            for (int h = 0; h < 2; ++h)
                #pragma unroll
                for (int t = 0; t < 4; ++t)
                    C2[t] = __builtin_amdgcn_mfma_f32_16x16x32_bf16(
                        A2m[h][t], BH[h], C2[t], 0, 0, 0);
            #pragma unroll
            for (int h = 0; h < 2; ++h)
                #pragma unroll
                for (int t = 0; t < 4; ++t)
                    C2[t] = __builtin_amdgcn_mfma_f32_16x16x32_bf16(
                        A2h[h][t], BM[h], C2[t], 0, 0, 0);
            #pragma unroll
            for (int h = 0; h < 2; ++h)
                #pragma unroll
                for (int t = 0; t < 4; ++t)
                    C2[t] = __builtin_amdgcn_mfma_f32_16x16x32_bf16(
                        A2h[h][t], BH[h], C2[t], 0, 0, 0);
            float dm = l3(C2);
            bool c = (dm < EPS_) && (cd >= 0.f) && (cd <= 1.f);
            hit = hit || c;
            if (!hit) cd += dm;
        }

        // ---- reflection net: quad q handles hidden j in [16q, 16q+16) ----
        const float px = fmaf(dx, cd, ox), py = fmaf(dy, cd, oy), pz = fmaf(dz, cd, oz);
        float r0 = 0.f, r1 = 0.f, r2 = 0.f;
        #pragma unroll 4
        for (int jj = 0; jj < 16; ++jj) {
            int j = quad * 16 + jj;
            float a = fmaf(px, Wr0[j],
                      fmaf(py, Wr0[64 + j],
                      fmaf(pz, Wr0[128 + j],
                      fmaf(dx, Wr0[192 + j],
                      fmaf(dy, Wr0[256 + j],
                      fmaf(dz, Wr0[320 + j], br0[j]))))));
            a = fmaxf(a, 0.f);
            r0 = fmaf(a, Wr1[j * 3 + 0], r0);
            r1 = fmaf(a, Wr1[j * 3 + 1], r1);
            r2 = fmaf(a, Wr1[j * 3 + 2], r2);
        }
        r0 += __shfl_xor(r0, 16, 64); r0 += __shfl_xor(r0, 32, 64);
        r1 += __shfl_xor(r1, 16, 64); r1 += __shfl_xor(r1, 32, 64);
        r2 += __shfl_xor(r2, 16, 64); r2 += __shfl_xor(r2, 32, 64);
        r0 = 1.f / (1.f + expf(-(r0 + br1[0])));
        r1 = 1.f / (1.f + expf(-(r1 + br1[1])));
        r2 = 1.f / (1.f + expf(-(r2 + br1[2])));
        if (!hit) { r0 = 0.f; r1 = 0.f; r2 = 0.f; }
        if (lane < 16) {
            float* op = out + (rayBase + lane) * 4;
            op[0] = r0; op[1] = r1; op[2] = r2;
        }
    } else {
        // =================== TPUT block: 65 independent evals ==============
        // Only the hi limbs needed (2-product L2): A2h in 32 registers.
        short8 A2h[2][4];
        #pragma unroll
        for (int h = 0; h < 2; ++h)
            #pragma unroll
            for (int t = 0; t < 4; ++t) {
                unsigned ph[4];
                #pragma unroll
                for (int jp = 0; jp < 4; ++jp) {
                    int k0 = 32 * h + quad * 8 + 2 * jp;
                    int j2 = 16 * t + m;
                    ph[jp] = packbf(__float_as_uint(W1[k0 * 64 + j2]),
                                    __float_as_uint(W1[(k0 + 1) * 64 + j2]));
                }
                A2h[h][t] = mk_frag(ph[0], ph[1], ph[2], ph[3]);
            }

        // i=0 at origin (== reference curr_min0), then t = STEP*i. unroll-1.
        float cm = 3.4e38f;
        #pragma unroll 1
        for (int i = 0; i <= 64; ++i) {
            float ti = STEP_ * (float)i;
            short8 BH[2], BM[2];
            front(fmaf(dx, ti, ox), fmaf(dy, ti, oy), fmaf(dz, ti, oz), BH, BM);
            // L2: 2 products (h,m)(h,h); 16 MFMAs. Same order as R15.
            float4v C2[4];
            #pragma unroll
            for (int t = 0; t < 4; ++t) C2[t] = b1v[t];
            #pragma unroll
            for (int h = 0; h < 2; ++h)
                #pragma unroll
                for (int t = 0; t < 4; ++t)
                    C2[t] = __builtin_amdgcn_mfma_f32_16x16x32_bf16(
                        A2h[h][t], BM[h], C2[t], 0, 0, 0);
            #pragma unroll
            for (int h = 0; h < 2; ++h)
                #pragma unroll
                for (int t = 0; t < 4; ++t)
                    C2[t] = __builtin_amdgcn_mfma_f32_16x16x32_bf16(
                        A2h[h][t], BH[h], C2[t], 0, 0, 0);
            float dt = l3(C2);
            cm = fminf(cm, dt);
        }
        if (lane < 16)
            out[(rayBase + lane) * 4 + 3] = cm;
    }
}

extern "C" void kernel_launch(void* const* d_in, const int* in_sizes, int n_in,
                              void* d_out, int out_size, void* d_ws, size_t ws_size,
                              hipStream_t stream) {
    const float* rays = (const float*)d_in[0];
    const float* W0   = (const float*)d_in[1];
    const float* b0   = (const float*)d_in[2];
    const float* W1   = (const float*)d_in[3];
    const float* b1   = (const float*)d_in[4];
    const float* W2   = (const float*)d_in[5];
    const float* b2   = (const float*)d_in[6];
    const float* Wr0  = (const float*)d_in[7];
    const float* br0  = (const float*)d_in[8];
    const float* Wr1  = (const float*)d_in[9];
    const float* br1  = (const float*)d_in[10];
    float* out = (float*)d_out;

    // 4096 single-wave blocks: even = march, odd = tput, 16 rays each.
    // Zero LDS; all weight state register-resident.
    // waves_per_eu(2,2): 256-VGPR budget (fits ~175-reg demand, no spill);
    // 2 waves/SIMD saturates the VALU pipe for this inst mix.
    hipLaunchKernelGGL(sdf_w7_k, dim3((NRAYS / 16) * 2), dim3(64), 0, stream,
                       rays, W0, b0, W1, b1, W2, b2, Wr0, br0, Wr1, br1, out);
}

// Round 5
// 187.748 us; speedup vs baseline: 1.0162x; 1.0023x over previous
//
#include <hip/hip_runtime.h>
#include <math.h>

// Problem constants
#define NRAYS        32768
#define MARCH_ITERS  64
#define EPS_         1e-4f
#define STEP_        ((1.0f + 1.0f/64.0f) / 64.0f)   // exact in fp32

typedef __attribute__((ext_vector_type(8)))  short    short8;   // 8 bf16
typedef __attribute__((ext_vector_type(4)))  float    float4v;  // C/D frag
typedef __attribute__((ext_vector_type(4)))  unsigned uint4v;

__device__ __forceinline__ short8 mk_frag(unsigned p0, unsigned p1,
                                          unsigned p2, unsigned p3) {
    uint4v v = {p0, p1, p2, p3};
    return __builtin_bit_cast(short8, v);
}

// One v_perm_b32: low16 = trunc-bf16(a), high16 = trunc-bf16(b).
__device__ __forceinline__ unsigned packbf(unsigned a, unsigned b) {
    return __builtin_amdgcn_perm(b, a, 0x07060302u);
}

// Exact 3-way truncation split: x == hi + mid + lo bit-exactly in fp32.
struct Split3 { unsigned h, m, l; };
__device__ __forceinline__ Split3 split3(float x) {
    unsigned xu = __float_as_uint(x);
    float xh = __uint_as_float(xu & 0xFFFF0000u);
    float r  = x - xh;                        // exact
    unsigned ru = __float_as_uint(r);
    float xm = __uint_as_float(ru & 0xFFFF0000u);
    float r2 = r - xm;                        // exact, fits bf16
    return { xu, ru, __float_as_uint(r2) };
}

// 2-way split: hi + residual (packbf of r truncates -> the mid limb).
struct Split2 { unsigned h, r; };
__device__ __forceinline__ Split2 split2(float x) {
    unsigned xu = __float_as_uint(x);
    float xh = __uint_as_float(xu & 0xFFFF0000u);
    float rr = x - xh;                        // exact residual
    return { xu, __float_as_uint(rr) };
}

// R19: 32 rays/wave, dual-chain ILP, one residency round.
// R18 post-mortem: spill gone (WRITE 9.2MB->1MB), zero in-loop memory,
// yet dur flat at 139us. Per-SIMD pipes only ~9% MFMA / ~15% VALU busy
// (the 32/59 readings are per-CU any-of-4-SIMD) -> the machine is ~75%
// stalled on serial dependency latency. R18 waves ran 2x faster than
// R15's (1.1k vs 4.7k cyc/eval) but waves_per_eu(2,2) caps residency at
// 8 waves/CU and 4096 waves forced TWO sequential rounds: 2 x 70us = 139.
// Fix: halve wave count. 2048 single-wave blocks (even=march, odd=tput),
// each wave owns 32 rays processed as TWO independent 16-ray chains per
// iteration against the SHARED register-resident weights. One round
// (2048 = 8 waves/CU = 2/SIMD exactly), and the two chains' ~500-cyc
// dependency chains interleave to fill stall slots. Register demand
// ~212 (A1 16 + A2h 32 + A2m 32 + b1v/w2v 32 + rays 12 + BH/BM 32 +
// C2 32 + temps) < 256 budget of waves_per_eu(2,2).
// Per-ray arithmetic (fragments, MFMA order, l3) is EXACTLY R18's ->
// absmax must stay 0.00390625.
// MFMA layouts (R6-verified): A[row=lane&15][k=quad*8+j],
// B[k=quad*8+j][col=lane&15], C/D col=lane&15 row=quad*4+reg.
// L1 hidden assignment H(t,q,r)=32*(t>>1)+8q+4*(t&1)+r -> in-lane C1->B2.
// Precision: march L2 = 3 products (m,h)(h,m)(h,h); tput L2 = 2 products.
__global__ __launch_bounds__(64)
__attribute__((amdgpu_waves_per_eu(2, 2)))
void sdf_w8_k(
    const float* __restrict__ rays,
    const float* __restrict__ W0,  const float* __restrict__ b0,
    const float* __restrict__ W1,  const float* __restrict__ b1,
    const float* __restrict__ W2,  const float* __restrict__ b2,
    const float* __restrict__ Wr0, const float* __restrict__ br0,
    const float* __restrict__ Wr1, const float* __restrict__ br1,
    float* __restrict__ out)
{
    const int lane = threadIdx.x;             // 0..63, one wave per block
    const int kind = blockIdx.x & 1;          // 0 = march, 1 = tput
    const int quad = lane >> 4;
    const int m    = lane & 15;
    const int rayBase = (blockIdx.x >> 1) * 32;

    // ---- per-lane rays: chain c handles ray rayBase + 16c + m ----
    float oxA[2], oyA[2], ozA[2], dxA[2], dyA[2], dzA[2];
    #pragma unroll
    for (int c = 0; c < 2; ++c) {
        const float* rp = rays + (rayBase + 16 * c + m) * 6;
        oxA[c] = rp[0]; oyA[c] = rp[1]; ozA[c] = rp[2];
        dxA[c] = rp[3]; dyA[c] = rp[4]; dzA[c] = rp[5];
    }

    // ---- A1: exact W0^T/b0 limbs, uniform per-quad K-slots (R9-verified) ----
    short8 A1[4];
    {
        const float* wbase = (quad == 0) ? W0 : (quad == 1) ? (W0 + 64)
                           : (quad == 2) ? (W0 + 128) : b0;
        #pragma unroll
        for (int t = 0; t < 4; ++t) {
            int j = 32 * (t >> 1) + 8 * (m >> 2) + 4 * (t & 1) + (m & 3);
            Split3 s = split3(wbase[j]);
            unsigned hh = packbf(s.h, s.h);
            unsigned hm = packbf(s.h, s.m);
            unsigned ml = packbf(s.m, s.l);
            unsigned l0 = packbf(s.l, 0u);
            bool is3 = (quad == 3);
            A1[t] = mk_frag(is3 ? hm : hh, is3 ? l0 : hm, is3 ? 0u : ml, 0u);
        }
    }

    // ---- b1 (C2 init) and W2 (L3), per-lane rows j2 = 16t+4q+r ----
    float4v b1v[4], w2v[4];
    #pragma unroll
    for (int t = 0; t < 4; ++t) {
        int base = 16 * t + 4 * quad;
        b1v[t] = (float4v){b1[base], b1[base + 1], b1[base + 2], b1[base + 3]};
        w2v[t] = (float4v){W2[base], W2[base + 1], W2[base + 2], W2[base + 3]};
    }
    const float b2s = b2[0];
    const float4v z4 = {0.f, 0.f, 0.f, 0.f};

    // ---- branchless exact B1 build (R9/R10-verified) ----
    auto buildB1 = [&](float px, float py, float pz) -> short8 {
        float c = (quad == 0) ? px : (quad == 1) ? py : pz;
        Split3 s = split3(c);
        unsigned d0 = packbf(s.h, s.m);
        unsigned d1 = packbf(s.l, s.h);
        unsigned d2 = packbf(s.m, s.h);
        if (quad == 3) { d0 = 0x3F803F80u; d1 = 0x00003F80u; d2 = 0u; }
        return mk_frag(d0, d1, d2, 0u);
    };

    // ---- shared front-end: pos -> exact L1 -> relu -> split2 pack ----
    auto front = [&](float px, float py, float pz, short8* BH, short8* BM) {
        short8 B1 = buildB1(px, py, pz);
        float4v C1[4];
        #pragma unroll
        for (int t = 0; t < 4; ++t)
            C1[t] = __builtin_amdgcn_mfma_f32_16x16x32_bf16(A1[t], B1, z4, 0, 0, 0);
        unsigned PH[4][2], PM[4][2];
        #pragma unroll
        for (int t = 0; t < 4; ++t) {
            float v0 = fmaxf(C1[t][0], 0.f), v1 = fmaxf(C1[t][1], 0.f);
            float v2 = fmaxf(C1[t][2], 0.f), v3 = fmaxf(C1[t][3], 0.f);
            unsigned u0 = __float_as_uint(v0), u1 = __float_as_uint(v1);
            unsigned u2 = __float_as_uint(v2), u3 = __float_as_uint(v3);
            PH[t][0] = packbf(u0, u1); PH[t][1] = packbf(u2, u3);
            float r0 = v0 - __uint_as_float(u0 & 0xFFFF0000u);
            float r1 = v1 - __uint_as_float(u1 & 0xFFFF0000u);
            float r2 = v2 - __uint_as_float(u2 & 0xFFFF0000u);
            float r3 = v3 - __uint_as_float(u3 & 0xFFFF0000u);
            PM[t][0] = packbf(__float_as_uint(r0), __float_as_uint(r1));
            PM[t][1] = packbf(__float_as_uint(r2), __float_as_uint(r3));
        }
        #pragma unroll
        for (int h = 0; h < 2; ++h) {
            BH[h] = mk_frag(PH[2 * h][0], PH[2 * h][1],
                            PH[2 * h + 1][0], PH[2 * h + 1][1]);
            BM[h] = mk_frag(PM[2 * h][0], PM[2 * h][1],
                            PM[2 * h + 1][0], PM[2 * h + 1][1]);
        }
    };

    // ---- L3: in-lane relu*W2, 2 cross-quad shuffles -> d at every lane ----
    auto l3 = [&](const float4v* C2) -> float {
        float q0 = 0.f, q1 = 0.f, q2 = 0.f, q3 = 0.f;
        #pragma unroll
        for (int t = 0; t < 4; ++t) {
            q0 = fmaf(fmaxf(C2[t][0], 0.f), w2v[t][0], q0);
            q1 = fmaf(fmaxf(C2[t][1], 0.f), w2v[t][1], q1);
            q2 = fmaf(fmaxf(C2[t][2], 0.f), w2v[t][2], q2);
            q3 = fmaf(fmaxf(C2[t][3], 0.f), w2v[t][3], q3);
        }
        float part = (q0 + q1) + (q2 + q3);
        part += __shfl_xor(part, 16, 64);
        part += __shfl_xor(part, 32, 64);
        return b2s + part;
    };

    if (kind == 0) {
        // =================== MARCH block: 2 chains x 64 sequential evals ===
        // Both W1 limb sets in registers: A2h (hi) + A2m (mid), 64 regs,
        // shared by both chains.
        short8 A2h[2][4], A2m[2][4];
        #pragma unroll
        for (int h = 0; h < 2; ++h)
            #pragma unroll
            for (int t = 0; t < 4; ++t) {
                unsigned pm[4], ph[4];
                #pragma unroll
                for (int jp = 0; jp < 4; ++jp) {
                    int k0 = 32 * h + quad * 8 + 2 * jp;
                    int j2 = 16 * t + m;
                    Split2 a = split2(W1[k0 * 64 + j2]);
                    Split2 b = split2(W1[(k0 + 1) * 64 + j2]);
                    pm[jp] = packbf(a.r, b.r);   // trunc(residual) == mid limb
                    ph[jp] = packbf(a.h, b.h);   // trunc(full) == hi limb
                }
                A2m[h][t] = mk_frag(pm[0], pm[1], pm[2], pm[3]);
                A2h[h][t] = mk_frag(ph[0], ph[1], ph[2], ph[3]);
            }

        bool  hit[2] = {false, false};
        float cd[2]  = {0.f, 0.f};
        #pragma unroll 1
        for (int it = 0; it < MARCH_ITERS; ++it) {
            if (__all(hit[0] & hit[1])) break;
            short8 BH[2][2], BM[2][2];
            #pragma unroll
            for (int c = 0; c < 2; ++c)
                front(fmaf(dxA[c], cd[c], oxA[c]),
                      fmaf(dyA[c], cd[c], oyA[c]),
                      fmaf(dzA[c], cd[c], ozA[c]), BH[c], BM[c]);
            // L2: 3 products, small first: (m,h)(h,m)(h,h); 24 MFMAs/chain.
            // Per-chain accumulation order identical to R18 -> bit-identical.
            float4v C2[2][4];
            #pragma unroll
            for (int c = 0; c < 2; ++c)
                #pragma unroll
                for (int t = 0; t < 4; ++t) C2[c][t] = b1v[t];
            #pragma unroll
            for (int h = 0; h < 2; ++h)
                #pragma unroll
                for (int c = 0; c < 2; ++c)
                    #pragma unroll
                    for (int t = 0; t < 4; ++t)
                        C2[c][t] = __builtin_amdgcn_mfma_f32_16x16x32_bf16(
                            A2m[h][t], BH[c][h], C2[c][t], 0, 0, 0);
            #pragma unroll
            for (int h = 0; h < 2; ++h)
                #pragma unroll
                for (int c = 0; c < 2; ++c)
                    #pragma unroll
                    for (int t = 0; t < 4; ++t)
                        C2[c][t] = __builtin_amdgcn_mfma_f32_16x16x32_bf16(
                            A2h[h][t], BM[c][h], C2[c][t], 0, 0, 0);
            #pragma unroll
            for (int h = 0; h < 2; ++h)
                #pragma unroll
                for (int c = 0; c < 2; ++c)
                    #pragma unroll
                    for (int t = 0; t < 4; ++t)
                        C2[c][t] = __builtin_amdgcn_mfma_f32_16x16x32_bf16(
                            A2h[h][t], BH[c][h], C2[c][t], 0, 0, 0);
            #pragma unroll
            for (int c = 0; c < 2; ++c) {
                float dm = l3(C2[c]);
                bool cc = (dm < EPS_) && (cd[c] >= 0.f) && (cd[c] <= 1.f);
                hit[c] = hit[c] || cc;
                if (!hit[c]) cd[c] += dm;
            }
        }

        // ---- reflection net x2: quad q handles hidden j in [16q, 16q+16) --
        #pragma unroll
        for (int c = 0; c < 2; ++c) {
            const float px = fmaf(dxA[c], cd[c], oxA[c]);
            const float py = fmaf(dyA[c], cd[c], oyA[c]);
            const float pz = fmaf(dzA[c], cd[c], ozA[c]);
            float r0 = 0.f, r1 = 0.f, r2 = 0.f;
            #pragma unroll 4
            for (int jj = 0; jj < 16; ++jj) {
                int j = quad * 16 + jj;
                float a = fmaf(px, Wr0[j],
                          fmaf(py, Wr0[64 + j],
                          fmaf(pz, Wr0[128 + j],
                          fmaf(dxA[c], Wr0[192 + j],
                          fmaf(dyA[c], Wr0[256 + j],
                          fmaf(dzA[c], Wr0[320 + j], br0[j]))))));
                a = fmaxf(a, 0.f);
                r0 = fmaf(a, Wr1[j * 3 + 0], r0);
                r1 = fmaf(a, Wr1[j * 3 + 1], r1);
                r2 = fmaf(a, Wr1[j * 3 + 2], r2);
            }
            r0 += __shfl_xor(r0, 16, 64); r0 += __shfl_xor(r0, 32, 64);
            r1 += __shfl_xor(r1, 16, 64); r1 += __shfl_xor(r1, 32, 64);
            r2 += __shfl_xor(r2, 16, 64); r2 += __shfl_xor(r2, 32, 64);
            r0 = 1.f / (1.f + expf(-(r0 + br1[0])));
            r1 = 1.f / (1.f + expf(-(r1 + br1[1])));
            r2 = 1.f / (1.f + expf(-(r2 + br1[2])));
            if (!hit[c]) { r0 = 0.f; r1 = 0.f; r2 = 0.f; }
            if (lane < 16) {
                float* op = out + (rayBase + 16 * c + lane) * 4;
                op[0] = r0; op[1] = r1; op[2] = r2;
            }
        }
    } else {
        // =================== TPUT block: 2 chains x 65 indep evals =========
        // Only the hi limbs needed (2-product L2): A2h in 32 registers.
        short8 A2h[2][4];
        #pragma unroll
        for (int h = 0; h < 2; ++h)
            #pragma unroll
            for (int t = 0; t < 4; ++t) {
                unsigned ph[4];
                #pragma unroll
                for (int jp = 0; jp < 4; ++jp) {
                    int k0 = 32 * h + quad * 8 + 2 * jp;
                    int j2 = 16 * t + m;
                    ph[jp] = packbf(__float_as_uint(W1[k0 * 64 + j2]),
                                    __float_as_uint(W1[(k0 + 1) * 64 + j2]));
                }
                A2h[h][t] = mk_frag(ph[0], ph[1], ph[2], ph[3]);
            }

        // i=0 at origin (== reference curr_min0), then t = STEP*i. unroll-1.
        float cm[2] = {3.4e38f, 3.4e38f};
        #pragma unroll 1
        for (int i = 0; i <= 64; ++i) {
            float ti = STEP_ * (float)i;
            short8 BH[2][2], BM[2][2];
            #pragma unroll
            for (int c = 0; c < 2; ++c)
                front(fmaf(dxA[c], ti, oxA[c]),
                      fmaf(dyA[c], ti, oyA[c]),
                      fmaf(dzA[c], ti, ozA[c]), BH[c], BM[c]);
            // L2: 2 products (h,m)(h,h); 16 MFMAs/chain. Same order as R18.
            float4v C2[2][4];
            #pragma unroll
            for (int c = 0; c < 2; ++c)
                #pragma unroll
                for (int t = 0; t < 4; ++t) C2[c][t] = b1v[t];
            #pragma unroll
            for (int h = 0; h < 2; ++h)
                #pragma unroll
                for (int c = 0; c < 2; ++c)
                    #pragma unroll
                    for (int t = 0; t < 4; ++t)
                        C2[c][t] = __builtin_amdgcn_mfma_f32_16x16x32_bf16(
                            A2h[h][t], BM[c][h], C2[c][t], 0, 0, 0);
            #pragma unroll
            for (int h = 0; h < 2; ++h)
                #pragma unroll
                for (int c = 0; c < 2; ++c)
                    #pragma unroll
                    for (int t = 0; t < 4; ++t)
                        C2[c][t] = __builtin_amdgcn_mfma_f32_16x16x32_bf16(
                            A2h[h][t], BH[c][h], C2[c][t], 0, 0, 0);
            #pragma unroll
            for (int c = 0; c < 2; ++c)
                cm[c] = fminf(cm[c], l3(C2[c]));
        }
        if (lane < 16) {
            out[(rayBase + lane) * 4 + 3]      = cm[0];
            out[(rayBase + 16 + lane) * 4 + 3] = cm[1];
        }
    }
}

extern "C" void kernel_launch(void* const* d_in, const int* in_sizes, int n_in,
                              void* d_out, int out_size, void* d_ws, size_t ws_size,
                              hipStream_t stream) {
    const float* rays = (const float*)d_in[0];
    const float* W0   = (const float*)d_in[1];
    const float* b0   = (const float*)d_in[2];
    const float* W1   = (const float*)d_in[3];
    const float* b1   = (const float*)d_in[4];
    const float* W2   = (const float*)d_in[5];
    const float* b2   = (const float*)d_in[6];
    const float* Wr0  = (const float*)d_in[7];
    const float* br0  = (const float*)d_in[8];
    const float* Wr1  = (const float*)d_in[9];
    const float* br1  = (const float*)d_in[10];
    float* out = (float*)d_out;

    // 2048 single-wave blocks: even = march, odd = tput, 32 rays each
    // (2 independent 16-ray chains per wave for ILP). Zero LDS; all
    // weights register-resident and shared by both chains.
    // waves_per_eu(2,2): 256-VGPR budget; 2048 waves = 8/CU = 2/SIMD,
    // everything resident in ONE round (R18 needed two).
    hipLaunchKernelGGL(sdf_w8_k, dim3((NRAYS / 32) * 2), dim3(64), 0, stream,
                       rays, W0, b0, W1, b1, W2, b2, Wr0, br0, Wr1, br1, out);
}

// Round 6
// 181.776 us; speedup vs baseline: 1.0496x; 1.0329x over previous
//
#include <hip/hip_runtime.h>
#include <math.h>

// Problem constants
#define NRAYS        32768
#define MARCH_ITERS  64
#define EPS_         1e-4f
#define STEP_        ((1.0f + 1.0f/64.0f) / 64.0f)   // exact in fp32

typedef __attribute__((ext_vector_type(8)))  short    short8;   // 8 bf16
typedef __attribute__((ext_vector_type(4)))  float    float4v;  // C/D frag
typedef __attribute__((ext_vector_type(4)))  unsigned uint4v;

__device__ __forceinline__ short8 mk_frag(unsigned p0, unsigned p1,
                                          unsigned p2, unsigned p3) {
    uint4v v = {p0, p1, p2, p3};
    return __builtin_bit_cast(short8, v);
}

// One v_perm_b32: low16 = trunc-bf16(a), high16 = trunc-bf16(b).
__device__ __forceinline__ unsigned packbf(unsigned a, unsigned b) {
    return __builtin_amdgcn_perm(b, a, 0x07060302u);
}

// Exact 3-way truncation split: x == hi + mid + lo bit-exactly in fp32.
struct Split3 { unsigned h, m, l; };
__device__ __forceinline__ Split3 split3(float x) {
    unsigned xu = __float_as_uint(x);
    float xh = __uint_as_float(xu & 0xFFFF0000u);
    float r  = x - xh;                        // exact
    unsigned ru = __float_as_uint(r);
    float xm = __uint_as_float(ru & 0xFFFF0000u);
    float r2 = r - xm;                        // exact, fits bf16
    return { xu, ru, __float_as_uint(r2) };
}

// 2-way split: hi + residual (packbf of r truncates -> the mid limb).
struct Split2 { unsigned h, r; };
__device__ __forceinline__ Split2 split2(float x) {
    unsigned xu = __float_as_uint(x);
    float xh = __uint_as_float(xu & 0xFFFF0000u);
    float rr = x - xh;                        // exact residual
    return { xu, __float_as_uint(rr) };
}

// R20: R18 structure with the residency cap LIFTED.
// Cross-round evidence (R15/R18/R19 all ~127-139us, VALUBusy 60-68%,
// same total evals, structure-independent): the kernel is VALU-ISSUE
// bound -- 0.60 x 136us = 82us of VALU issue/SIMD, matching the hand
// count (~530k evals x ~170 wave-insts x 2cyc / 1024 SIMDs). It sits at
// 60% (not ~100%) because R18's waves_per_eu(2,2) max=2 CAP forced 4096
// waves through TWO residency rounds (R19 halved waves instead -> still
// only 2/SIMD interleave). With ~1.3-1.6 waves/SIMD, each wave's MFMA
// block (which stalls its own wave) leaves the VALU pipe idle ~1/3 of
// the time (VALU 60 + MFMA 32 = 92% serialized per-wave).
// Fix: waves_per_eu(2,8) -- min 2 keeps the 256-VGPR allocator budget
// (R18 used 88; 4x88 <= 512 so 4/SIMD is feasible), max 8 lets all 4096
// waves be resident in ONE round: 4 waves/SIMD, wave A's MFMA hides
// under B/C/D's VALU. Everything else is R18 bit-for-bit ->
// absmax must stay 0.00390625.
// MFMA layouts (R6-verified): A[row=lane&15][k=quad*8+j],
// B[k=quad*8+j][col=lane&15], C/D col=lane&15 row=quad*4+reg.
// L1 hidden assignment H(t,q,r)=32*(t>>1)+8q+4*(t&1)+r -> in-lane C1->B2.
// Precision: march L2 = 3 products (m,h)(h,m)(h,h); tput L2 = 2 products.
__global__ __launch_bounds__(64)
__attribute__((amdgpu_waves_per_eu(2, 8)))
void sdf_w9_k(
    const float* __restrict__ rays,
    const float* __restrict__ W0,  const float* __restrict__ b0,
    const float* __restrict__ W1,  const float* __restrict__ b1,
    const float* __restrict__ W2,  const float* __restrict__ b2,
    const float* __restrict__ Wr0, const float* __restrict__ br0,
    const float* __restrict__ Wr1, const float* __restrict__ br1,
    float* __restrict__ out)
{
    const int lane = threadIdx.x;             // 0..63, one wave per block
    const int kind = blockIdx.x & 1;          // 0 = march, 1 = tput
    const int quad = lane >> 4;
    const int m    = lane & 15;
    const int rayBase = (blockIdx.x >> 1) * 16;

    // ---- per-lane ray (ray = rayBase + m, replicated over quads) ----
    const float* rp = rays + (rayBase + m) * 6;
    const float ox = rp[0], oy = rp[1], oz = rp[2];
    const float dx = rp[3], dy = rp[4], dz = rp[5];

    // ---- A1: exact W0^T/b0 limbs, uniform per-quad K-slots (R9-verified) ----
    short8 A1[4];
    {
        const float* wbase = (quad == 0) ? W0 : (quad == 1) ? (W0 + 64)
                           : (quad == 2) ? (W0 + 128) : b0;
        #pragma unroll
        for (int t = 0; t < 4; ++t) {
            int j = 32 * (t >> 1) + 8 * (m >> 2) + 4 * (t & 1) + (m & 3);
            Split3 s = split3(wbase[j]);
            unsigned hh = packbf(s.h, s.h);
            unsigned hm = packbf(s.h, s.m);
            unsigned ml = packbf(s.m, s.l);
            unsigned l0 = packbf(s.l, 0u);
            bool is3 = (quad == 3);
            A1[t] = mk_frag(is3 ? hm : hh, is3 ? l0 : hm, is3 ? 0u : ml, 0u);
        }
    }

    // ---- b1 (C2 init) and W2 (L3), per-lane rows j2 = 16t+4q+r ----
    float4v b1v[4], w2v[4];
    #pragma unroll
    for (int t = 0; t < 4; ++t) {
        int base = 16 * t + 4 * quad;
        b1v[t] = (float4v){b1[base], b1[base + 1], b1[base + 2], b1[base + 3]};
        w2v[t] = (float4v){W2[base], W2[base + 1], W2[base + 2], W2[base + 3]};
    }
    const float b2s = b2[0];
    const float4v z4 = {0.f, 0.f, 0.f, 0.f};

    // ---- branchless exact B1 build (R9/R10-verified) ----
    auto buildB1 = [&](float px, float py, float pz) -> short8 {
        float c = (quad == 0) ? px : (quad == 1) ? py : pz;
        Split3 s = split3(c);
        unsigned d0 = packbf(s.h, s.m);
        unsigned d1 = packbf(s.l, s.h);
        unsigned d2 = packbf(s.m, s.h);
        if (quad == 3) { d0 = 0x3F803F80u; d1 = 0x00003F80u; d2 = 0u; }
        return mk_frag(d0, d1, d2, 0u);
    };

    // ---- shared front-end: pos -> exact L1 -> relu -> split2 pack ----
    auto front = [&](float px, float py, float pz, short8* BH, short8* BM) {
        short8 B1 = buildB1(px, py, pz);
        float4v C1[4];
        #pragma unroll
        for (int t = 0; t < 4; ++t)
            C1[t] = __builtin_amdgcn_mfma_f32_16x16x32_bf16(A1[t], B1, z4, 0, 0, 0);
        unsigned PH[4][2], PM[4][2];
        #pragma unroll
        for (int t = 0; t < 4; ++t) {
            float v0 = fmaxf(C1[t][0], 0.f), v1 = fmaxf(C1[t][1], 0.f);
            float v2 = fmaxf(C1[t][2], 0.f), v3 = fmaxf(C1[t][3], 0.f);
            unsigned u0 = __float_as_uint(v0), u1 = __float_as_uint(v1);
            unsigned u2 = __float_as_uint(v2), u3 = __float_as_uint(v3);
            PH[t][0] = packbf(u0, u1); PH[t][1] = packbf(u2, u3);
            float r0 = v0 - __uint_as_float(u0 & 0xFFFF0000u);
            float r1 = v1 - __uint_as_float(u1 & 0xFFFF0000u);
            float r2 = v2 - __uint_as_float(u2 & 0xFFFF0000u);
            float r3 = v3 - __uint_as_float(u3 & 0xFFFF0000u);
            PM[t][0] = packbf(__float_as_uint(r0), __float_as_uint(r1));
            PM[t][1] = packbf(__float_as_uint(r2), __float_as_uint(r3));
        }
        #pragma unroll
        for (int h = 0; h < 2; ++h) {
            BH[h] = mk_frag(PH[2 * h][0], PH[2 * h][1],
                            PH[2 * h + 1][0], PH[2 * h + 1][1]);
            BM[h] = mk_frag(PM[2 * h][0], PM[2 * h][1],
                            PM[2 * h + 1][0], PM[2 * h + 1][1]);
        }
    };

    // ---- L3: in-lane relu*W2, 2 cross-quad shuffles -> d at every lane ----
    auto l3 = [&](const float4v* C2) -> float {
        float q0 = 0.f, q1 = 0.f, q2 = 0.f, q3 = 0.f;
        #pragma unroll
        for (int t = 0; t < 4; ++t) {
            q0 = fmaf(fmaxf(C2[t][0], 0.f), w2v[t][0], q0);
            q1 = fmaf(fmaxf(C2[t][1], 0.f), w2v[t][1], q1);
            q2 = fmaf(fmaxf(C2[t][2], 0.f), w2v[t][2], q2);
            q3 = fmaf(fmaxf(C2[t][3], 0.f), w2v[t][3], q3);
        }
        float part = (q0 + q1) + (q2 + q3);
        part += __shfl_xor(part, 16, 64);
        part += __shfl_xor(part, 32, 64);
        return b2s + part;
    };

    if (kind == 0) {
        // =================== MARCH block: 64 sequential evals ==============
        // Both W1 limb sets live in registers: A2h (hi) + A2m (mid), 64 regs.
        short8 A2h[2][4], A2m[2][4];
        #pragma unroll
        for (int h = 0; h < 2; ++h)
            #pragma unroll
            for (int t = 0; t < 4; ++t) {
                unsigned pm[4], ph[4];
                #pragma unroll
                for (int jp = 0; jp < 4; ++jp) {
                    int k0 = 32 * h + quad * 8 + 2 * jp;
                    int j2 = 16 * t + m;
                    Split2 a = split2(W1[k0 * 64 + j2]);
                    Split2 b = split2(W1[(k0 + 1) * 64 + j2]);
                    pm[jp] = packbf(a.r, b.r);   // trunc(residual) == mid limb
                    ph[jp] = packbf(a.h, b.h);   // trunc(full) == hi limb
                }
                A2m[h][t] = mk_frag(pm[0], pm[1], pm[2], pm[3]);
                A2h[h][t] = mk_frag(ph[0], ph[1], ph[2], ph[3]);
            }

        bool  hit = false;
        float cd  = 0.f;
        #pragma unroll 1
        for (int it = 0; it < MARCH_ITERS; ++it) {
            if (__all(hit)) break;
            short8 BH[2], BM[2];
            front(fmaf(dx, cd, ox), fmaf(dy, cd, oy), fmaf(dz, cd, oz), BH, BM);
            // L2: 3 products, small first: (m,h)(h,m)(h,h); 24 MFMAs.
            // Same accumulation order as R18 -> bit-identical.
            float4v C2[4];
            #pragma unroll
            for (int t = 0; t < 4; ++t) C2[t] = b1v[t];
            #pragma unroll
            for (int h = 0; h < 2; ++h)
                #pragma unroll
                for (int t = 0; t < 4; ++t)
                    C2[t] = __builtin_amdgcn_mfma_f32_16x16x32_bf16(
                        A2m[h][t], BH[h], C2[t], 0, 0, 0);
            #pragma unroll
            for (int h = 0; h < 2; ++h)
                #pragma unroll
                for (int t = 0; t < 4; ++t)
                    C2[t] = __builtin_amdgcn_mfma_f32_16x16x32_bf16(
                        A2h[h][t], BM[h], C2[t], 0, 0, 0);
            #pragma unroll
            for (int h = 0; h < 2; ++h)
                #pragma unroll
                for (int t = 0; t < 4; ++t)
                    C2[t] = __builtin_amdgcn_mfma_f32_16x16x32_bf16(
                        A2h[h][t], BH[h], C2[t], 0, 0, 0);
            float dm = l3(C2);
            bool c = (dm < EPS_) && (cd >= 0.f) && (cd <= 1.f);
            hit = hit || c;
            if (!hit) cd += dm;
        }

        // ---- reflection net: quad q handles hidden j in [16q, 16q+16) ----
        const float px = fmaf(dx, cd, ox), py = fmaf(dy, cd, oy), pz = fmaf(dz, cd, oz);
        float r0 = 0.f, r1 = 0.f, r2 = 0.f;
        #pragma unroll 4
        for (int jj = 0; jj < 16; ++jj) {
            int j = quad * 16 + jj;
            float a = fmaf(px, Wr0[j],
                      fmaf(py, Wr0[64 + j],
                      fmaf(pz, Wr0[128 + j],
                      fmaf(dx, Wr0[192 + j],
                      fmaf(dy, Wr0[256 + j],
                      fmaf(dz, Wr0[320 + j], br0[j]))))));
            a = fmaxf(a, 0.f);
            r0 = fmaf(a, Wr1[j * 3 + 0], r0);
            r1 = fmaf(a, Wr1[j * 3 + 1], r1);
            r2 = fmaf(a, Wr1[j * 3 + 2], r2);
        }
        r0 += __shfl_xor(r0, 16, 64); r0 += __shfl_xor(r0, 32, 64);
        r1 += __shfl_xor(r1, 16, 64); r1 += __shfl_xor(r1, 32, 64);
        r2 += __shfl_xor(r2, 16, 64); r2 += __shfl_xor(r2, 32, 64);
        r0 = 1.f / (1.f + expf(-(r0 + br1[0])));
        r1 = 1.f / (1.f + expf(-(r1 + br1[1])));
        r2 = 1.f / (1.f + expf(-(r2 + br1[2])));
        if (!hit) { r0 = 0.f; r1 = 0.f; r2 = 0.f; }
        if (lane < 16) {
            float* op = out + (rayBase + lane) * 4;
            op[0] = r0; op[1] = r1; op[2] = r2;
        }
    } else {
        // =================== TPUT block: 65 independent evals ==============
        // Only the hi limbs needed (2-product L2): A2h in 32 registers.
        short8 A2h[2][4];
        #pragma unroll
        for (int h = 0; h < 2; ++h)
            #pragma unroll
            for (int t = 0; t < 4; ++t) {
                unsigned ph[4];
                #pragma unroll
                for (int jp = 0; jp < 4; ++jp) {
                    int k0 = 32 * h + quad * 8 + 2 * jp;
                    int j2 = 16 * t + m;
                    ph[jp] = packbf(__float_as_uint(W1[k0 * 64 + j2]),
                                    __float_as_uint(W1[(k0 + 1) * 64 + j2]));
                }
                A2h[h][t] = mk_frag(ph[0], ph[1], ph[2], ph[3]);
            }

        // i=0 at origin (== reference curr_min0), then t = STEP*i. unroll-1.
        float cm = 3.4e38f;
        #pragma unroll 1
        for (int i = 0; i <= 64; ++i) {
            float ti = STEP_ * (float)i;
            short8 BH[2], BM[2];
            front(fmaf(dx, ti, ox), fmaf(dy, ti, oy), fmaf(dz, ti, oz), BH, BM);
            // L2: 2 products (h,m)(h,h); 16 MFMAs. Same order as R18.
            float4v C2[4];
            #pragma unroll
            for (int t = 0; t < 4; ++t) C2[t] = b1v[t];
            #pragma unroll
            for (int h = 0; h < 2; ++h)
                #pragma unroll
                for (int t = 0; t < 4; ++t)
                    C2[t] = __builtin_amdgcn_mfma_f32_16x16x32_bf16(
                        A2h[h][t], BM[h], C2[t], 0, 0, 0);
            #pragma unroll
            for (int h = 0; h < 2; ++h)
                #pragma unroll
                for (int t = 0; t < 4; ++t)
                    C2[t] = __builtin_amdgcn_mfma_f32_16x16x32_bf16(
                        A2h[h][t], BH[h], C2[t], 0, 0, 0);
            float dt = l3(C2);
            cm = fminf(cm, dt);
        }
        if (lane < 16)
            out[(rayBase + lane) * 4 + 3] = cm;
    }
}

extern "C" void kernel_launch(void* const* d_in, const int* in_sizes, int n_in,
                              void* d_out, int out_size, void* d_ws, size_t ws_size,
                              hipStream_t stream) {
    const float* rays = (const float*)d_in[0];
    const float* W0   = (const float*)d_in[1];
    const float* b0   = (const float*)d_in[2];
    const float* W1   = (const float*)d_in[3];
    const float* b1   = (const float*)d_in[4];
    const float* W2   = (const float*)d_in[5];
    const float* b2   = (const float*)d_in[6];
    const float* Wr0  = (const float*)d_in[7];
    const float* br0  = (const float*)d_in[8];
    const float* Wr1  = (const float*)d_in[9];
    const float* br1  = (const float*)d_in[10];
    float* out = (float*)d_out;

    // 4096 single-wave blocks: even = march, odd = tput, 16 rays each.
    // Zero LDS; all weight state register-resident (VGPR ~88).
    // waves_per_eu(2,8): 256-reg budget (min=2) but NO residency cap ->
    // all 4096 waves resident in ONE round at 4 waves/SIMD, so one
    // wave's MFMA overlaps the other three's VALU issue.
    hipLaunchKernelGGL(sdf_w9_k, dim3((NRAYS / 16) * 2), dim3(64), 0, stream,
                       rays, W0, b0, W1, b1, W2, b2, Wr0, br0, Wr1, br1, out);
}